// Round 6
// baseline (242.674 us; speedup 1.0000x reference)
//
#include <hip/hip_runtime.h>

#define NNODES 100000
#define NEDGES 3200000
#define ETOT   (NEDGES + NNODES)
#define NEG_SLOPE 0.2f

#define NPB 64                               // nodes per bucket (dst >> 6)
#define NBUCK ((NNODES + NPB - 1) / NPB)     // 1563 buckets
#define NCHUNK 256                           // edge chunks
#define CHUNK_E ((ETOT + NCHUNK - 1) / NCHUNK)  // 12891 edges/chunk
#define M2 (NBUCK * NCHUNK)                  // 400128 (chunk-scan length)
#define NSB2 ((M2 + 511) / 512)              // 782

// bf16 storage via raw ushort — no hip_fp16.h / hip_bf16.h dependency.
__device__ __forceinline__ unsigned short f2bf(float f) {
    unsigned u = __float_as_uint(f);
    u += 0x7FFFu + ((u >> 16) & 1u);         // round-to-nearest-even
    return (unsigned short)(u >> 16);
}
__device__ __forceinline__ float bf2f(unsigned short h) {
    return __uint_as_float(((unsigned)h) << 16);
}

// edge e in [0, NEDGES): src = ei[e], dst = ei[NEDGES+e]
// edge e in [NEDGES, ETOT): self-loop, src = dst = e - NEDGES
__device__ __forceinline__ void edge_sd(int e, const int* __restrict__ ei, int& s, int& d) {
    if (e < NEDGES) { s = ei[e]; d = ei[NEDGES + e]; }
    else            { s = e - NEDGES; d = s; }
}

__device__ __forceinline__ float lrelu(float v) {
    return v > 0.0f ? v : NEG_SLOPE * v;
}

// ---- reduction primitives (round-23, proven-correct) ----
// In-row (16-lane) exchange as DPP row rotation fused into the add. After the
// 4 rotations every lane holds its row's full sum. row_ror:N ctrl = 0x120+N.
template<int CTRL>
__device__ __forceinline__ float dpp_add(float v) {
    return v + __int_as_float(__builtin_amdgcn_mov_dpp(__float_as_int(v), CTRL, 0xF, 0xF, true));
}
// Cross-row within a 32-lane half: ds_swizzle xor-16 (offset 0x401F).
__device__ __forceinline__ float swz16_add(float v) {
    return v + __int_as_float(__builtin_amdgcn_ds_swizzle(__float_as_int(v), 0x401F));
}
// Sum over all 16 lanes of each row (rotations 1,2,4,8).
__device__ __forceinline__ float row16_sum(float v) {
    v = dpp_add<0x121>(v);   // row_ror:1
    v = dpp_add<0x122>(v);   // row_ror:2
    v = dpp_add<0x124>(v);   // row_ror:4
    v = dpp_add<0x128>(v);   // row_ror:8
    return v;
}
// Full 64-lane sum; every lane ends with the total.
__device__ __forceinline__ float wave64_sum(float v) {
    v = row16_sum(v);
    v = swz16_add(v);
    v += __shfl_xor(v, 32);
    return v;
}

// ---------------- deterministic chunked bucket sort ----------------

__global__ void chunk_hist(const int* __restrict__ ei, int* __restrict__ H) {
    __shared__ int h[NBUCK];
    int c = blockIdx.x;
    for (int i = threadIdx.x; i < NBUCK; i += blockDim.x) h[i] = 0;
    __syncthreads();
    int lo = c * CHUNK_E, hi = lo + CHUNK_E; if (hi > ETOT) hi = ETOT;
    for (int e = lo + threadIdx.x; e < hi; e += blockDim.x) {
        int d = (e < NEDGES) ? ei[NEDGES + e] : (e - NEDGES);
        atomicAdd(&h[d >> 6], 1);
    }
    __syncthreads();
    for (int i = threadIdx.x; i < NBUCK; i += blockDim.x) H[c * NBUCK + i] = h[i];
}

// 3-phase exclusive scan of H in bucket-major order.
// Linear index i = b*NCHUNK + c (NCHUNK=256: b = i>>8, c = i&255); value = H[c*NBUCK+b].
__global__ void cscan_local(const int* __restrict__ H, int* __restrict__ off,
                            int* __restrict__ bsum2) {
    __shared__ int arr[512];
    int blk = blockIdx.x, t = threadIdx.x;
    int i = blk * 512 + t;
    int v = (i < M2) ? H[(i & (NCHUNK - 1)) * NBUCK + (i >> 8)] : 0;
    arr[t] = v;
    __syncthreads();
    for (int o = 1; o < 512; o <<= 1) {
        int u = (t >= o) ? arr[t - o] : 0;
        __syncthreads();
        arr[t] += u;
        __syncthreads();
    }
    if (i < M2) off[i] = arr[t] - v;
    if (t == 511) bsum2[blk] = arr[t];
}

__global__ void cscan_bsum(const int* __restrict__ bsum2, int* __restrict__ boff2) {
    __shared__ int arr[1024];
    int t = threadIdx.x;
    int v = (t < NSB2) ? bsum2[t] : 0;
    arr[t] = v;
    __syncthreads();
    for (int o = 1; o < 1024; o <<= 1) {
        int u = (t >= o) ? arr[t - o] : 0;
        __syncthreads();
        arr[t] += u;
        __syncthreads();
    }
    if (t < NSB2) boff2[t] = arr[t] - v;
}

__global__ void cscan_add(int* __restrict__ off, const int* __restrict__ boff2) {
    int i = blockIdx.x * 512 + threadIdx.x;
    if (i < M2) off[i] += boff2[blockIdx.x];
}

// LDS-staged scatter (round-22, proven: WRITE_SIZE 67-78MB -> off top-5).
// Scan the chunk's histogram row for local compaction, scatter into LDS (98KB),
// copy out linearly -- entry at local slot i of bucket b lands at gbase[b]+i.
// Grid is 256 blocks = 1/CU, so the big LDS costs no occupancy.
__global__ __launch_bounds__(1024)
void chunk_scatter(const int* __restrict__ ei, const int* __restrict__ off,
                   const int* __restrict__ H, int* __restrict__ pairs) {
    __shared__ int plds[CHUNK_E];            // 51564 B: packed pair per local slot
    __shared__ unsigned short blds[CHUNK_E]; // 25782 B: bucket id per local slot
    __shared__ int sc[2048];                 //  8192 B: inclusive scan of counts
    __shared__ int lcur[NBUCK];              //  6252 B: local alloc cursor
    __shared__ int gbase[NBUCK];             //  6252 B: off[b,c] - lpref[b]
    int c = blockIdx.x, t = threadIdx.x;
    // load this chunk's bucket counts
    for (int b = t; b < 2048; b += 1024) sc[b] = (b < NBUCK) ? H[c * NBUCK + b] : 0;
    __syncthreads();
    // Hillis-Steele inclusive scan over 2048 entries, 2 per thread
    for (int o = 1; o < 2048; o <<= 1) {
        int i1 = t + 1024;
        int v0 = (t >= o) ? sc[t - o] : 0;
        int v1 = (i1 >= o) ? sc[i1 - o] : 0;
        __syncthreads();
        sc[t] += v0; sc[i1] += v1;
        __syncthreads();
    }
    for (int b = t; b < NBUCK; b += 1024) {
        int excl = (b == 0) ? 0 : sc[b - 1];        // exclusive local prefix
        lcur[b]  = excl;
        gbase[b] = off[b * NCHUNK + c] - excl;
    }
    __syncthreads();
    int lo = c * CHUNK_E, hi = lo + CHUNK_E; if (hi > ETOT) hi = ETOT;
    int n = hi - lo;
    for (int e = lo + t; e < hi; e += 1024) {
        int s, d; edge_sd(e, ei, s, d);
        int b = d >> 6;
        int slot = atomicAdd(&lcur[b], 1);
        plds[slot] = ((d & 63) << 17) | s;          // src < 2^17
        blds[slot] = (unsigned short)b;
    }
    __syncthreads();
    for (int i = t; i < n; i += 1024)
        pairs[gbase[blds[i]] + i] = plds[i];        // coalesced within segments
}

__global__ void fine_sort2(const int* __restrict__ off, const int* __restrict__ pairs,
                           int* __restrict__ row_start, int* __restrict__ csr_src) {
    __shared__ int arr[NPB];
    __shared__ int cur[NPB];
    int b = blockIdx.x;
    int t = threadIdx.x;
    int base = off[b * NCHUNK];
    int bend = (b == NBUCK - 1) ? ETOT : off[(b + 1) * NCHUNK];
    if (t < NPB) arr[t] = 0;
    __syncthreads();
    for (int i = base + t; i < bend; i += blockDim.x)
        atomicAdd(&arr[pairs[i] >> 17], 1);
    __syncthreads();
    int v = (t < NPB) ? arr[t] : 0;
    __syncthreads();
    for (int o = 1; o < NPB; o <<= 1) {           // inclusive scan over 64 counts
        int u = (t < NPB && t >= o) ? arr[t - o] : 0;
        __syncthreads();
        if (t < NPB) arr[t] += u;
        __syncthreads();
    }
    if (t < NPB) {
        int node = b * NPB + t;
        int start = base + arr[t] - v;            // exclusive prefix
        cur[t] = start;
        if (node < NNODES) row_start[node] = start;
    }
    if (b == NBUCK - 1 && t == 0) row_start[NNODES] = ETOT;
    __syncthreads();
    for (int i = base + t; i < bend; i += blockDim.x) {
        int p = pairs[i];
        int slot = atomicAdd(&cur[p >> 17], 1);
        csr_src[slot] = p & 0x1FFFF;
    }
}

// ---------------- attention-vector precompute (proven) ----------------
// cvec layout: [0,1]=c1s  [2,3]=c1d  [4..19]=c2s  [20..35]=c2d
__global__ void prep(const float* __restrict__ W1, const float* __restrict__ as1,
                     const float* __restrict__ ad1, const float* __restrict__ W2,
                     const float* __restrict__ as2, const float* __restrict__ ad2,
                     float* __restrict__ cvec) {
    int t = threadIdx.x;
    if (t < 2) {
        float s = 0.f, d = 0.f;
        for (int f = 0; f < 16; ++f) { s += W1[t * 16 + f] * as1[f]; d += W1[t * 16 + f] * ad1[f]; }
        cvec[t] = s; cvec[2 + t] = d;
    }
    if (t < 16) {
        float s = 0.f, d = 0.f;
        for (int f = 0; f < 64; ++f) { s += W2[t * 64 + f] * as2[f]; d += W2[t * 64 + f] * ad2[f]; }
        cvec[4 + t] = s; cvec[20 + t] = d;
    }
}

__global__ void alpha1(const float* __restrict__ x, const float* __restrict__ cvec,
                       float* __restrict__ as_, float* __restrict__ ad_) {
    int n = blockIdx.x * blockDim.x + threadIdx.x;
    if (n >= NNODES) return;
    float2 xv = ((const float2*)x)[n];
    as_[n] = xv.x * cvec[0] + xv.y * cvec[1];
    ad_[n] = xv.x * cvec[2] + xv.y * cvec[3];
}

// ---------------- layer 1: aggregate x (2 feats), @W1 in epilogue -------------
// One edge per lane (stride 64), software-pipelined; DPP/swz reduction; alpha2
// fused in epilogue. Zero LDS, zero barriers; 256-thread blocks. (round-23)
__global__ void agg_l1(const int* __restrict__ row_start, const int* __restrict__ csr_src,
                       const float* __restrict__ as_, const float* __restrict__ ad_,
                       const float* __restrict__ x, const float* __restrict__ W1,
                       const float* __restrict__ b1, const float* __restrict__ cvec,
                       unsigned short* __restrict__ g,
                       float* __restrict__ as2_, float* __restrict__ ad2_) {
    int wave = threadIdx.x >> 6, lane = threadIdx.x & 63;
    int node = blockIdx.x * 4 + wave;          // always < NNODES (exact grid)
    int base = row_start[node], end = row_start[node + 1];
    float adv = ad_[node];
    float a0 = 0.f, a1 = 0.f, ss = 0.f;
    const float2* x2 = (const float2*)x;
    int last = end - 1;                        // end > base always (self-loop)
    int i = base + lane;
    int sj = csr_src[min(i, last)];
    float asv = as_[sj];
    float2 xv = x2[sj];
    while (i < end) {
        int inext = i + 64;
        int sjn = csr_src[min(inext, last)];   // prefetch next iteration
        float asn = as_[sjn];
        float2 xn = x2[sjn];
        float w = __expf(lrelu(asv + adv));
        ss += w;
        a0 += w * xv.x;
        a1 += w * xv.y;
        i = inext; sj = sjn; asv = asn; xv = xn;
    }
    // full 64-lane sum: 4 DPP rotations (in-row) + swizzle16 + shfl32
    a0 = wave64_sum(a0); a1 = wave64_sum(a1); ss = wave64_sum(ss);
    int f = lane & 15;                         // all lanes compute feature f
    float v = (a0 * W1[f] + a1 * W1[16 + f]) / ss + b1[f];
    float vr = v > 0.f ? v : 0.f;
    if (lane < 16) g[node * 16 + lane] = f2bf(vr);
    // fused alpha2 (f32): sum over the 16 features of this row (row-local)
    float s2 = vr * cvec[4 + f];
    float d2 = vr * cvec[20 + f];
    s2 = row16_sum(s2); d2 = row16_sum(d2);
    if (lane == 0) { as2_[node] = s2; ad2_[node] = d2; }
}

// ---------------- layer 2: aggregate bf16 g, @W2 in epilogue ------------------
// Round-24 rewrite: ONE EDGE PER LANE, full 32B g-row per lane (2x dwordx4).
// Old structure (16 groups x 4 lanes, stride 16) paid ~2.6 serial gather
// round-trips per wave and issued 4x-redundant csr/as_ loads; two epilogue
// optimizations in a row were neutral -> edge-loop latency is the bottleneck.
// Now deg<=64 nodes (virtually all, Poisson(33)) do a SINGLE round-trip with
// ~4 outstanding loads/lane (256/wave). csr reads fully coalesced, 1 exp/edge.
// Epilogue: 17 full-wave DPP/swz sums; every lane then holds all 16 feature
// totals -> readlane broadcast eliminated; W2 matvec straight from registers.
__global__ void agg_l2(const int* __restrict__ row_start, const int* __restrict__ csr_src,
                       const float* __restrict__ as_, const float* __restrict__ ad_,
                       const unsigned short* __restrict__ g, const float* __restrict__ W2,
                       const float* __restrict__ b2, float* __restrict__ out) {
    int wave = threadIdx.x >> 6, lane = threadIdx.x & 63;
    int node = blockIdx.x * 4 + wave; // always < NNODES (exact grid)
    int base = row_start[node], end = row_start[node + 1];
    float adv = ad_[node];
    float acc[16];
#pragma unroll
    for (int k = 0; k < 16; ++k) acc[k] = 0.f;
    float ss = 0.f;
    for (int i = base + lane; i < end; i += 64) {   // one iteration for deg<=64
        int sj = csr_src[i];                        // coalesced (consecutive i)
        float w = __expf(lrelu(as_[sj] + adv));
        ss += w;
        const uint4* gp = (const uint4*)(g + sj * 16);  // row 32B-aligned
        uint4 u0 = gp[0], u1 = gp[1];                   // full row, 2 insts
        unsigned uu[8] = {u0.x, u0.y, u0.z, u0.w, u1.x, u1.y, u1.z, u1.w};
#pragma unroll
        for (int j = 0; j < 8; ++j) {
            acc[2 * j]     += w * __uint_as_float(uu[j] << 16);
            acc[2 * j + 1] += w * __uint_as_float(uu[j] & 0xFFFF0000u);
        }
    }
    // 17 full-wave sums (4 DPP + swz16 + shfl32 each); independent chains.
#pragma unroll
    for (int k = 0; k < 16; ++k) acc[k] = wave64_sum(acc[k]);
    ss = wave64_sum(ss);
    // Every lane holds all 16 totals: W2 matvec directly from registers.
    float o = 0.f;
#pragma unroll
    for (int k = 0; k < 16; ++k)
        o += acc[k] * W2[k * 64 + lane];           // coalesced W2 column
    o = o / ss + b2[lane];                         // single normalize per node
    out[(size_t)node * 64 + lane] = o > 0.f ? o : 0.f;
}

extern "C" void kernel_launch(void* const* d_in, const int* in_sizes, int n_in,
                              void* d_out, int out_size, void* d_ws, size_t ws_size,
                              hipStream_t stream) {
    const float* x     = (const float*)d_in[0];
    const int*   ei    = (const int*)  d_in[1];
    const float* W1    = (const float*)d_in[2];
    const float* as1w  = (const float*)d_in[3];
    const float* ad1w  = (const float*)d_in[4];
    const float* b1    = (const float*)d_in[5];
    const float* W2    = (const float*)d_in[6];
    const float* as2w  = (const float*)d_in[7];
    const float* ad2w  = (const float*)d_in[8];
    const float* b2    = (const float*)d_in[9];
    float* out = (float*)d_out;

    // ws layout (4-byte elems, ~37 MB; 40.4 MB proven available):
    //   row_start[N+4] | csr_src[ETOT] | g[N*16 bf16, in former float slot] |
    //   asb[N] | adb[N] | as2b[N] | ad2b[N] | cvec[64] | pairs[ETOT] |
    //   H[M2] | off[M2] | bsum2[1024] | boff2[1024]
    int* row_start = (int*)d_ws;
    int* csr_src   = row_start + (NNODES + 4);
    float* gslot   = (float*)(csr_src + ETOT);   // N*16 floats reserved
    unsigned short* gbuf = (unsigned short*)gslot;  // N*16 bf16 used
    float* asb     = gslot + (size_t)NNODES * 16;
    float* adb     = asb + NNODES;
    float* as2b    = adb + NNODES;
    float* ad2b    = as2b + NNODES;
    float* cvec    = ad2b + NNODES;              // 36 floats used
    int* pairs     = (int*)(cvec + 64);          // ETOT
    int* H         = pairs + ETOT;               // M2
    int* off       = H + M2;                     // M2
    int* bsum2     = off + M2;                   // 1024
    int* boff2     = bsum2 + 1024;               // 1024

    const int B = 256;
    const int NB = (NNODES + B - 1) / B;

    // ---- CSR build: deterministic chunked bucket sort ----
    chunk_hist<<<NCHUNK, 1024, 0, stream>>>(ei, H);
    cscan_local<<<NSB2, 512, 0, stream>>>(H, off, bsum2);
    cscan_bsum<<<1, 1024, 0, stream>>>(bsum2, boff2);
    cscan_add<<<NSB2, 512, 0, stream>>>(off, boff2);
    chunk_scatter<<<NCHUNK, 1024, 0, stream>>>(ei, off, H, pairs);
    fine_sort2<<<NBUCK, B, 0, stream>>>(off, pairs, row_start, csr_src);

    // ---- attention precompute ----
    prep<<<1, 64, 0, stream>>>(W1, as1w, ad1w, W2, as2w, ad2w, cvec);

    // ---- Layer 1: alphas from x, aggregate x, W1 in epilogue (g stored bf16);
    //      layer-2 alphas fused into the epilogue (alpha2 kernel eliminated) ----
    alpha1<<<NB, B, 0, stream>>>(x, cvec, asb, adb);
    agg_l1<<<NNODES / 4, B, 0, stream>>>(row_start, csr_src, asb, adb, x, W1, b1,
                                         cvec, gbuf, as2b, ad2b);

    // ---- Layer 2: aggregate bf16 g, W2 in epilogue ----
    agg_l2<<<NNODES / 4, B, 0, stream>>>(row_start, csr_src, as2b, ad2b, gbuf, W2, b2, out);
}

// Round 7
// 239.177 us; speedup vs baseline: 1.0146x; 1.0146x over previous
//
#include <hip/hip_runtime.h>

#define NNODES 100000
#define NEDGES 3200000
#define ETOT   (NEDGES + NNODES)
#define NEG_SLOPE 0.2f

#define NPB 64                               // nodes per bucket (dst >> 6)
#define NBUCK ((NNODES + NPB - 1) / NPB)     // 1563 buckets
#define NCHUNK 256                           // edge chunks
#define CHUNK_E ((ETOT + NCHUNK - 1) / NCHUNK)  // 12891 edges/chunk
#define M2 (NBUCK * NCHUNK)                  // 400128 (chunk-scan length)
#define NSB2 ((M2 + 511) / 512)              // 782

// bf16 storage via raw ushort — no hip_fp16.h / hip_bf16.h dependency.
__device__ __forceinline__ unsigned short f2bf(float f) {
    unsigned u = __float_as_uint(f);
    u += 0x7FFFu + ((u >> 16) & 1u);         // round-to-nearest-even
    return (unsigned short)(u >> 16);
}
__device__ __forceinline__ float bf2f(unsigned short h) {
    return __uint_as_float(((unsigned)h) << 16);
}

// edge e in [0, NEDGES): src = ei[e], dst = ei[NEDGES+e]
// edge e in [NEDGES, ETOT): self-loop, src = dst = e - NEDGES
__device__ __forceinline__ void edge_sd(int e, const int* __restrict__ ei, int& s, int& d) {
    if (e < NEDGES) { s = ei[e]; d = ei[NEDGES + e]; }
    else            { s = e - NEDGES; d = s; }
}

__device__ __forceinline__ float lrelu(float v) {
    return v > 0.0f ? v : NEG_SLOPE * v;
}

// Broadcast from a compile-time lane: v_readlane -> SGPR (scalar pipe, no DS op).
__device__ __forceinline__ float bcast_lane(float v, int lane_imm) {
    return __int_as_float(__builtin_amdgcn_readlane(__float_as_int(v), lane_imm));
}

// ---- cross-lane primitives ----
template<int CTRL>
__device__ __forceinline__ float dpp_mov(float v) {
    return __int_as_float(__builtin_amdgcn_mov_dpp(__float_as_int(v), CTRL, 0xF, 0xF, true));
}
template<int CTRL>
__device__ __forceinline__ float dpp_add(float v) { return v + dpp_mov<CTRL>(v); }
template<int IMM>
__device__ __forceinline__ float swz(float v) {
    return __int_as_float(__builtin_amdgcn_ds_swizzle(__float_as_int(v), IMM));
}
// Cross-row within a 32-lane half: ds_swizzle xor-16.
__device__ __forceinline__ float swz16_add(float v) { return v + swz<0x401F>(v); }
// Sum over all 16 lanes of each row (rotations 1,2,4,8).
__device__ __forceinline__ float row16_sum(float v) {
    v = dpp_add<0x121>(v);   // row_ror:1
    v = dpp_add<0x122>(v);   // row_ror:2
    v = dpp_add<0x124>(v);   // row_ror:4
    v = dpp_add<0x128>(v);   // row_ror:8
    return v;
}
// Full 64-lane sum; every lane ends with the total.
__device__ __forceinline__ float wave64_sum(float v) {
    v = row16_sum(v);
    v = swz16_add(v);
    v += __shfl_xor(v, 32);
    return v;
}

// ---------------- deterministic chunked bucket sort ----------------

__global__ void chunk_hist(const int* __restrict__ ei, int* __restrict__ H) {
    __shared__ int h[NBUCK];
    int c = blockIdx.x;
    for (int i = threadIdx.x; i < NBUCK; i += blockDim.x) h[i] = 0;
    __syncthreads();
    int lo = c * CHUNK_E, hi = lo + CHUNK_E; if (hi > ETOT) hi = ETOT;
    for (int e = lo + threadIdx.x; e < hi; e += blockDim.x) {
        int d = (e < NEDGES) ? ei[NEDGES + e] : (e - NEDGES);
        atomicAdd(&h[d >> 6], 1);
    }
    __syncthreads();
    for (int i = threadIdx.x; i < NBUCK; i += blockDim.x) H[c * NBUCK + i] = h[i];
}

// 3-phase exclusive scan of H in bucket-major order.
// Linear index i = b*NCHUNK + c (NCHUNK=256: b = i>>8, c = i&255); value = H[c*NBUCK+b].
__global__ void cscan_local(const int* __restrict__ H, int* __restrict__ off,
                            int* __restrict__ bsum2) {
    __shared__ int arr[512];
    int blk = blockIdx.x, t = threadIdx.x;
    int i = blk * 512 + t;
    int v = (i < M2) ? H[(i & (NCHUNK - 1)) * NBUCK + (i >> 8)] : 0;
    arr[t] = v;
    __syncthreads();
    for (int o = 1; o < 512; o <<= 1) {
        int u = (t >= o) ? arr[t - o] : 0;
        __syncthreads();
        arr[t] += u;
        __syncthreads();
    }
    if (i < M2) off[i] = arr[t] - v;
    if (t == 511) bsum2[blk] = arr[t];
}

__global__ void cscan_bsum(const int* __restrict__ bsum2, int* __restrict__ boff2) {
    __shared__ int arr[1024];
    int t = threadIdx.x;
    int v = (t < NSB2) ? bsum2[t] : 0;
    arr[t] = v;
    __syncthreads();
    for (int o = 1; o < 1024; o <<= 1) {
        int u = (t >= o) ? arr[t - o] : 0;
        __syncthreads();
        arr[t] += u;
        __syncthreads();
    }
    if (t < NSB2) boff2[t] = arr[t] - v;
}

__global__ void cscan_add(int* __restrict__ off, const int* __restrict__ boff2) {
    int i = blockIdx.x * 512 + threadIdx.x;
    if (i < M2) off[i] += boff2[blockIdx.x];
}

// LDS-staged scatter (round-22, proven: WRITE_SIZE 67-78MB -> off top-5).
__global__ __launch_bounds__(1024)
void chunk_scatter(const int* __restrict__ ei, const int* __restrict__ off,
                   const int* __restrict__ H, int* __restrict__ pairs) {
    __shared__ int plds[CHUNK_E];            // 51564 B: packed pair per local slot
    __shared__ unsigned short blds[CHUNK_E]; // 25782 B: bucket id per local slot
    __shared__ int sc[2048];                 //  8192 B: inclusive scan of counts
    __shared__ int lcur[NBUCK];              //  6252 B: local alloc cursor
    __shared__ int gbase[NBUCK];             //  6252 B: off[b,c] - lpref[b]
    int c = blockIdx.x, t = threadIdx.x;
    for (int b = t; b < 2048; b += 1024) sc[b] = (b < NBUCK) ? H[c * NBUCK + b] : 0;
    __syncthreads();
    for (int o = 1; o < 2048; o <<= 1) {
        int i1 = t + 1024;
        int v0 = (t >= o) ? sc[t - o] : 0;
        int v1 = (i1 >= o) ? sc[i1 - o] : 0;
        __syncthreads();
        sc[t] += v0; sc[i1] += v1;
        __syncthreads();
    }
    for (int b = t; b < NBUCK; b += 1024) {
        int excl = (b == 0) ? 0 : sc[b - 1];        // exclusive local prefix
        lcur[b]  = excl;
        gbase[b] = off[b * NCHUNK + c] - excl;
    }
    __syncthreads();
    int lo = c * CHUNK_E, hi = lo + CHUNK_E; if (hi > ETOT) hi = ETOT;
    int n = hi - lo;
    for (int e = lo + t; e < hi; e += 1024) {
        int s, d; edge_sd(e, ei, s, d);
        int b = d >> 6;
        int slot = atomicAdd(&lcur[b], 1);
        plds[slot] = ((d & 63) << 17) | s;          // src < 2^17
        blds[slot] = (unsigned short)b;
    }
    __syncthreads();
    for (int i = t; i < n; i += 1024)
        pairs[gbase[blds[i]] + i] = plds[i];        // coalesced within segments
}

__global__ void fine_sort2(const int* __restrict__ off, const int* __restrict__ pairs,
                           int* __restrict__ row_start, int* __restrict__ csr_src) {
    __shared__ int arr[NPB];
    __shared__ int cur[NPB];
    int b = blockIdx.x;
    int t = threadIdx.x;
    int base = off[b * NCHUNK];
    int bend = (b == NBUCK - 1) ? ETOT : off[(b + 1) * NCHUNK];
    if (t < NPB) arr[t] = 0;
    __syncthreads();
    for (int i = base + t; i < bend; i += blockDim.x)
        atomicAdd(&arr[pairs[i] >> 17], 1);
    __syncthreads();
    int v = (t < NPB) ? arr[t] : 0;
    __syncthreads();
    for (int o = 1; o < NPB; o <<= 1) {           // inclusive scan over 64 counts
        int u = (t < NPB && t >= o) ? arr[t - o] : 0;
        __syncthreads();
        if (t < NPB) arr[t] += u;
        __syncthreads();
    }
    if (t < NPB) {
        int node = b * NPB + t;
        int start = base + arr[t] - v;            // exclusive prefix
        cur[t] = start;
        if (node < NNODES) row_start[node] = start;
    }
    if (b == NBUCK - 1 && t == 0) row_start[NNODES] = ETOT;
    __syncthreads();
    for (int i = base + t; i < bend; i += blockDim.x) {
        int p = pairs[i];
        int slot = atomicAdd(&cur[p >> 17], 1);
        csr_src[slot] = p & 0x1FFFF;
    }
}

// ---------------- attention-vector precompute (proven) ----------------
// cvec layout: [0,1]=c1s  [2,3]=c1d  [4..19]=c2s  [20..35]=c2d
__global__ void prep(const float* __restrict__ W1, const float* __restrict__ as1,
                     const float* __restrict__ ad1, const float* __restrict__ W2,
                     const float* __restrict__ as2, const float* __restrict__ ad2,
                     float* __restrict__ cvec) {
    int t = threadIdx.x;
    if (t < 2) {
        float s = 0.f, d = 0.f;
        for (int f = 0; f < 16; ++f) { s += W1[t * 16 + f] * as1[f]; d += W1[t * 16 + f] * ad1[f]; }
        cvec[t] = s; cvec[2 + t] = d;
    }
    if (t < 16) {
        float s = 0.f, d = 0.f;
        for (int f = 0; f < 64; ++f) { s += W2[t * 64 + f] * as2[f]; d += W2[t * 64 + f] * ad2[f]; }
        cvec[4 + t] = s; cvec[20 + t] = d;
    }
}

__global__ void alpha1(const float* __restrict__ x, const float* __restrict__ cvec,
                       float* __restrict__ as_, float* __restrict__ ad_) {
    int n = blockIdx.x * blockDim.x + threadIdx.x;
    if (n >= NNODES) return;
    float2 xv = ((const float2*)x)[n];
    as_[n] = xv.x * cvec[0] + xv.y * cvec[1];
    ad_[n] = xv.x * cvec[2] + xv.y * cvec[3];
}

// ---------------- layer 1: aggregate x (2 feats), @W1 in epilogue -------------
// One edge per lane (stride 64), software-pipelined; DPP/swz reduction; alpha2
// fused in epilogue. Zero LDS, zero barriers; 256-thread blocks.
__global__ void agg_l1(const int* __restrict__ row_start, const int* __restrict__ csr_src,
                       const float* __restrict__ as_, const float* __restrict__ ad_,
                       const float* __restrict__ x, const float* __restrict__ W1,
                       const float* __restrict__ b1, const float* __restrict__ cvec,
                       unsigned short* __restrict__ g,
                       float* __restrict__ as2_, float* __restrict__ ad2_) {
    int wave = threadIdx.x >> 6, lane = threadIdx.x & 63;
    int node = blockIdx.x * 4 + wave;          // always < NNODES (exact grid)
    int base = row_start[node], end = row_start[node + 1];
    float adv = ad_[node];
    float a0 = 0.f, a1 = 0.f, ss = 0.f;
    const float2* x2 = (const float2*)x;
    int last = end - 1;                        // end > base always (self-loop)
    int i = base + lane;
    int sj = csr_src[min(i, last)];
    float asv = as_[sj];
    float2 xv = x2[sj];
    while (i < end) {
        int inext = i + 64;
        int sjn = csr_src[min(inext, last)];   // prefetch next iteration
        float asn = as_[sjn];
        float2 xn = x2[sjn];
        float w = __expf(lrelu(asv + adv));
        ss += w;
        a0 += w * xv.x;
        a1 += w * xv.y;
        i = inext; sj = sjn; asv = asn; xv = xn;
    }
    a0 = wave64_sum(a0); a1 = wave64_sum(a1); ss = wave64_sum(ss);
    int f = lane & 15;                         // all lanes compute feature f
    float v = (a0 * W1[f] + a1 * W1[16 + f]) / ss + b1[f];
    float vr = v > 0.f ? v : 0.f;
    if (lane < 16) g[node * 16 + lane] = f2bf(vr);
    // fused alpha2 (f32): sum over the 16 features of this row (row-local)
    float s2 = vr * cvec[4 + f];
    float d2 = vr * cvec[20 + f];
    s2 = row16_sum(s2); d2 = row16_sum(d2);
    if (lane == 0) { as2_[node] = s2; ad2_[node] = d2; }
}

// ---------------- layer 2: aggregate bf16 g, @W2 in epilogue ------------------
// One edge per lane, full 32B g-row per lane (round-24). Round-25: the 16
// independent wave64_sum's (~190 insts, 64x-redundant: every lane computed
// every feature's total) replaced by a TRANSPOSED butterfly: per stage each
// lane keeps the accumulator half selected by the lane bit and sends the
// discarded half (keep + exchange(send)); 16->8->4->2->1 over bits 0..3
// (quad_perm DPP for xor1/xor2, ds_swizzle for xor4/xor8). After 4 stages
// lane l holds the row-sum of feature l&15; swz16+shfl32 finish. ~64 insts.
// The 16 totals live in lanes 0..15 -> readlane broadcasts feed the W2 matvec.
__global__ void agg_l2(const int* __restrict__ row_start, const int* __restrict__ csr_src,
                       const float* __restrict__ as_, const float* __restrict__ ad_,
                       const unsigned short* __restrict__ g, const float* __restrict__ W2,
                       const float* __restrict__ b2, float* __restrict__ out) {
    int wave = threadIdx.x >> 6, lane = threadIdx.x & 63;
    int node = blockIdx.x * 4 + wave; // always < NNODES (exact grid)
    int base = row_start[node], end = row_start[node + 1];
    float adv = ad_[node];
    float acc[16];
#pragma unroll
    for (int k = 0; k < 16; ++k) acc[k] = 0.f;
    float ss = 0.f;
    for (int i = base + lane; i < end; i += 64) {   // one iteration for deg<=64
        int sj = csr_src[i];                        // coalesced (consecutive i)
        float w = __expf(lrelu(as_[sj] + adv));
        ss += w;
        const uint4* gp = (const uint4*)(g + sj * 16);  // row 32B-aligned
        uint4 u0 = gp[0], u1 = gp[1];                   // full row, 2 insts
        unsigned uu[8] = {u0.x, u0.y, u0.z, u0.w, u1.x, u1.y, u1.z, u1.w};
#pragma unroll
        for (int j = 0; j < 8; ++j) {
            acc[2 * j]     += w * __uint_as_float(uu[j] << 16);
            acc[2 * j + 1] += w * __uint_as_float(uu[j] & 0xFFFF0000u);
        }
    }
    // ---- transposed butterfly reduce: lane l ends with total of feature l&15
    // stage bit0: partner l^1 (quad_perm [1,0,3,2] = 0xB1)
#pragma unroll
    for (int j = 0; j < 8; ++j) {
        float keep = (lane & 1) ? acc[2 * j + 1] : acc[2 * j];
        float send = (lane & 1) ? acc[2 * j]     : acc[2 * j + 1];
        acc[j] = keep + dpp_mov<0xB1>(send);
    }
    // stage bit1: partner l^2 (quad_perm [2,3,0,1] = 0x4E)
#pragma unroll
    for (int j = 0; j < 4; ++j) {
        float keep = (lane & 2) ? acc[2 * j + 1] : acc[2 * j];
        float send = (lane & 2) ? acc[2 * j]     : acc[2 * j + 1];
        acc[j] = keep + dpp_mov<0x4E>(send);
    }
    // stage bit2: partner l^4 (ds_swizzle xor4)
#pragma unroll
    for (int j = 0; j < 2; ++j) {
        float keep = (lane & 4) ? acc[2 * j + 1] : acc[2 * j];
        float send = (lane & 4) ? acc[2 * j]     : acc[2 * j + 1];
        acc[j] = keep + swz<0x101F>(send);
    }
    // stage bit3: partner l^8 (ds_swizzle xor8)
    float r;
    {
        float keep = (lane & 8) ? acc[1] : acc[0];
        float send = (lane & 8) ? acc[0] : acc[1];
        r = keep + swz<0x201F>(send);
    }
    // cross-row: xor16 + xor32 -> full-wave total of feature lane&15
    r = swz16_add(r);
    r += __shfl_xor(r, 32);
    float st = wave64_sum(ss);
    // Feature k total lives in lane k (k=0..15): readlane + coalesced W2 column.
    float o = 0.f;
#pragma unroll
    for (int k = 0; k < 16; ++k)
        o += bcast_lane(r, k) * W2[k * 64 + lane];
    o = o / st + b2[lane];                         // single normalize per node
    out[(size_t)node * 64 + lane] = o > 0.f ? o : 0.f;
}

extern "C" void kernel_launch(void* const* d_in, const int* in_sizes, int n_in,
                              void* d_out, int out_size, void* d_ws, size_t ws_size,
                              hipStream_t stream) {
    const float* x     = (const float*)d_in[0];
    const int*   ei    = (const int*)  d_in[1];
    const float* W1    = (const float*)d_in[2];
    const float* as1w  = (const float*)d_in[3];
    const float* ad1w  = (const float*)d_in[4];
    const float* b1    = (const float*)d_in[5];
    const float* W2    = (const float*)d_in[6];
    const float* as2w  = (const float*)d_in[7];
    const float* ad2w  = (const float*)d_in[8];
    const float* b2    = (const float*)d_in[9];
    float* out = (float*)d_out;

    // ws layout (4-byte elems, ~37 MB; 40.4 MB proven available):
    //   row_start[N+4] | csr_src[ETOT] | g[N*16 bf16, in former float slot] |
    //   asb[N] | adb[N] | as2b[N] | ad2b[N] | cvec[64] | pairs[ETOT] |
    //   H[M2] | off[M2] | bsum2[1024] | boff2[1024]
    int* row_start = (int*)d_ws;
    int* csr_src   = row_start + (NNODES + 4);
    float* gslot   = (float*)(csr_src + ETOT);   // N*16 floats reserved
    unsigned short* gbuf = (unsigned short*)gslot;  // N*16 bf16 used
    float* asb     = gslot + (size_t)NNODES * 16;
    float* adb     = asb + NNODES;
    float* as2b    = adb + NNODES;
    float* ad2b    = as2b + NNODES;
    float* cvec    = ad2b + NNODES;              // 36 floats used
    int* pairs     = (int*)(cvec + 64);          // ETOT
    int* H         = pairs + ETOT;               // M2
    int* off       = H + M2;                     // M2
    int* bsum2     = off + M2;                   // 1024
    int* boff2     = bsum2 + 1024;               // 1024

    const int B = 256;
    const int NB = (NNODES + B - 1) / B;

    // ---- CSR build: deterministic chunked bucket sort ----
    chunk_hist<<<NCHUNK, 1024, 0, stream>>>(ei, H);
    cscan_local<<<NSB2, 512, 0, stream>>>(H, off, bsum2);
    cscan_bsum<<<1, 1024, 0, stream>>>(bsum2, boff2);
    cscan_add<<<NSB2, 512, 0, stream>>>(off, boff2);
    chunk_scatter<<<NCHUNK, 1024, 0, stream>>>(ei, off, H, pairs);
    fine_sort2<<<NBUCK, B, 0, stream>>>(off, pairs, row_start, csr_src);

    // ---- attention precompute ----
    prep<<<1, 64, 0, stream>>>(W1, as1w, ad1w, W2, as2w, ad2w, cvec);

    // ---- Layer 1: alphas from x, aggregate x, W1 in epilogue (g stored bf16);
    //      layer-2 alphas fused into the epilogue (alpha2 kernel eliminated) ----
    alpha1<<<NB, B, 0, stream>>>(x, cvec, asb, adb);
    agg_l1<<<NNODES / 4, B, 0, stream>>>(row_start, csr_src, asb, adb, x, W1, b1,
                                         cvec, gbuf, as2b, ad2b);

    // ---- Layer 2: aggregate bf16 g, W2 in epilogue ----
    agg_l2<<<NNODES / 4, B, 0, stream>>>(row_start, csr_src, as2b, ad2b, gbuf, W2, b2, out);
}